// Round 2
// baseline (1131.750 us; speedup 1.0000x reference)
//
#include <hip/hip_runtime.h>
#include <math.h>

// CapsuleLayer dynamic routing, fused routing passes.
// Shapes (hardcoded per reference): B=32, N=2048, D=32, J=64, K=32, 3 iters.
//
// Algebra: b starts at 0 => logits for iter2 are u.v1, for iter3 u.(v1+v2).
// So each routing iteration is ONE fused pass over u_hat:
//   per (b,n): t_j = u.v ; c = softmax_j(t) ; s += c*u   (registers only)
//
// Two workspace tiers selected by ws_size (constant per session -> identical
// work every call, graph-capture safe):
//   f32 tier  (~605 MB): u_hat stored f32
//   bf16 tier (~336 MB): u_hat stored bf16 (RNE), v1 still exact (s1 partials
//                        accumulate from f32 registers inside k1)

#define BB 32
#define NN 2048
#define DD 32
#define JJ 64
#define KK 32

// ---------------- bf16 helpers (manual RNE) ----------------
__device__ inline unsigned short f2bf(float f) {
    union { float f; unsigned u; } c; c.f = f;
    unsigned r = c.u + 0x7FFFu + ((c.u >> 16) & 1u);
    return (unsigned short)(r >> 16);
}
__device__ inline float bf2f(unsigned short h) {
    union { unsigned u; float f; } c; c.u = ((unsigned)h) << 16;
    return c.f;
}
__device__ inline void store_u2(float* p, float a, float b) {
    float2 o; o.x = a; o.y = b;
    *reinterpret_cast<float2*>(p) = o;
}
__device__ inline void store_u2(unsigned short* p, float a, float b) {
    ushort2 o; o.x = f2bf(a); o.y = f2bf(b);
    *reinterpret_cast<ushort2*>(p) = o;
}
__device__ inline float4 load_u4(const float* p) {
    return *reinterpret_cast<const float4*>(p);
}
__device__ inline float4 load_u4(const unsigned short* p) {
    ushort4 v = *reinterpret_cast<const ushort4*>(p);
    float4 o; o.x = bf2f(v.x); o.y = bf2f(v.y); o.z = bf2f(v.z); o.w = bf2f(v.w);
    return o;
}

// ---------------------------------------------------------------------------
// Kernel 1: u_hat[b][n][j][k] = sum_d W[n][j][d][k] * x[b][n][d], plus
// f32-register accumulation of sum_n u_hat -> p1 partials (v1 stays exact).
// grid (128, 4): block = (ncb: 16 n's, jq: 16 j's), 256 threads (4 waves).
// thread: j = jq*16 + w*4 + l/16, k0 = 2*(l%16); owns (j,k0,k0+1) for ALL b
// -> W is thread-exclusive (512 MB total W traffic), x broadcast from LDS.
// ---------------------------------------------------------------------------
template <typename UT>
__global__ __launch_bounds__(256, 2)
void k1_uhat(const float* __restrict__ x, const float* __restrict__ W,
             UT* __restrict__ u, float* __restrict__ p1) {
    __shared__ float xt[DD * 36];  // xt[d*36 + b], padded stride 36
    const int t   = threadIdx.x;
    const int ncb = blockIdx.x;    // 0..127 -> n in [ncb*16, ncb*16+16)
    const int jq  = blockIdx.y;    // 0..3
    const int w   = t >> 6;
    const int l   = t & 63;
    const int j   = jq * 16 + w * 4 + (l >> 4);
    const int k0  = (l & 15) * 2;

    float s1a[BB][2];
#pragma unroll
    for (int b = 0; b < BB; ++b) { s1a[b][0] = 0.f; s1a[b][1] = 0.f; }

    for (int ni = 0; ni < 16; ++ni) {
        const int n = ncb * 16 + ni;
        __syncthreads();
        {   // stage x[:, n, :] transposed into LDS (coalesced float4 reads)
            const int b  = t >> 3;
            const int d0 = (t & 7) * 4;
            const float4 xv = *reinterpret_cast<const float4*>(&x[(b * NN + n) * DD + d0]);
            xt[(d0 + 0) * 36 + b] = xv.x;
            xt[(d0 + 1) * 36 + b] = xv.y;
            xt[(d0 + 2) * 36 + b] = xv.z;
            xt[(d0 + 3) * 36 + b] = xv.w;
        }
        __syncthreads();

        float acc[BB][2];
#pragma unroll
        for (int b = 0; b < BB; ++b) { acc[b][0] = 0.f; acc[b][1] = 0.f; }

        const float* wp = &W[(n * JJ + j) * DD * KK + k0];  // d-stride KK
        for (int d = 0; d < DD; ++d) {
            const float2 wv = *reinterpret_cast<const float2*>(&wp[d * KK]);
#pragma unroll
            for (int bc = 0; bc < 8; ++bc) {
                const float4 xv = *reinterpret_cast<const float4*>(&xt[d * 36 + bc * 4]);
                acc[bc * 4 + 0][0] += xv.x * wv.x;  acc[bc * 4 + 0][1] += xv.x * wv.y;
                acc[bc * 4 + 1][0] += xv.y * wv.x;  acc[bc * 4 + 1][1] += xv.y * wv.y;
                acc[bc * 4 + 2][0] += xv.z * wv.x;  acc[bc * 4 + 2][1] += xv.z * wv.y;
                acc[bc * 4 + 3][0] += xv.w * wv.x;  acc[bc * 4 + 3][1] += xv.w * wv.y;
            }
        }
#pragma unroll
        for (int b = 0; b < BB; ++b) {
            store_u2(&u[((size_t)(b * NN + n) * JJ + j) * KK + k0], acc[b][0], acc[b][1]);
            s1a[b][0] += acc[b][0];
            s1a[b][1] += acc[b][1];
        }
    }
#pragma unroll
    for (int b = 0; b < BB; ++b) {  // p1[ncb][b][j][k0..k0+1]
        float2 o; o.x = s1a[b][0]; o.y = s1a[b][1];
        *reinterpret_cast<float2*>(&p1[((ncb * BB + b) * JJ + j) * KK + k0]) = o;
    }
}

// ---------------------------------------------------------------------------
// Fused routing pass (iterations 2 and 3).
// grid (32 b, 32 nc): 256 threads = 4 waves; wave handles 16 n's.
// Per lane, it in 0..7: j = it*8 + l/8, k = (l%8)*4..+3.
// v-fragment + s-accumulator in registers; per-wave partial chunk writes
// (no atomics, no LDS).
// ---------------------------------------------------------------------------
template <typename UT>
__global__ __launch_bounds__(256)
void k_route(const UT* __restrict__ u, const float* __restrict__ v,
             float* __restrict__ pout) {
    const int b  = blockIdx.x;
    const int nc = blockIdx.y;
    const int t  = threadIdx.x;
    const int w  = t >> 6;
    const int l  = t & 63;
    const int lo = ((l >> 3) << 5) + ((l & 7) << 2);  // (l/8)*32 + (l%8)*4

    float vr[8][4];
#pragma unroll
    for (int it = 0; it < 8; ++it) {
        const float4 vv = *reinterpret_cast<const float4*>(&v[b * (JJ * KK) + it * 256 + lo]);
        vr[it][0] = vv.x; vr[it][1] = vv.y; vr[it][2] = vv.z; vr[it][3] = vv.w;
    }
    float sacc[8][4];
#pragma unroll
    for (int it = 0; it < 8; ++it)
        for (int q = 0; q < 4; ++q) sacc[it][q] = 0.f;

    for (int i = 0; i < 16; ++i) {
        const int n = nc * 64 + i * 4 + w;
        const UT* up = &u[(size_t)(b * NN + n) * (JJ * KK)];
        float ur[8][4];
        float tt[8];
#pragma unroll
        for (int it = 0; it < 8; ++it) {
            const float4 uv = load_u4(&up[it * 256 + lo]);
            ur[it][0] = uv.x; ur[it][1] = uv.y; ur[it][2] = uv.z; ur[it][3] = uv.w;
            tt[it] = uv.x * vr[it][0] + uv.y * vr[it][1] + uv.z * vr[it][2] + uv.w * vr[it][3];
        }
#pragma unroll
        for (int it = 0; it < 8; ++it) {   // k-reduce within 8-lane j-groups
            tt[it] += __shfl_xor(tt[it], 1);
            tt[it] += __shfl_xor(tt[it], 2);
            tt[it] += __shfl_xor(tt[it], 4);
        }
        // softmax over all 64 j (8 per lane, disjoint j-sets across groups)
        float m = tt[0];
#pragma unroll
        for (int it = 1; it < 8; ++it) m = fmaxf(m, tt[it]);
        m = fmaxf(m, __shfl_xor(m, 8));
        m = fmaxf(m, __shfl_xor(m, 16));
        m = fmaxf(m, __shfl_xor(m, 32));
        float e[8];
        float S = 0.f;
#pragma unroll
        for (int it = 0; it < 8; ++it) { e[it] = __expf(tt[it] - m); S += e[it]; }
        S += __shfl_xor(S, 8);
        S += __shfl_xor(S, 16);
        S += __shfl_xor(S, 32);
        const float rS = 1.0f / S;
#pragma unroll
        for (int it = 0; it < 8; ++it) {
            const float c = e[it] * rS;
            sacc[it][0] += c * ur[it][0];
            sacc[it][1] += c * ur[it][1];
            sacc[it][2] += c * ur[it][2];
            sacc[it][3] += c * ur[it][3];
        }
    }
    const int chunk = nc * 4 + w;  // 0..127
#pragma unroll
    for (int it = 0; it < 8; ++it) {
        float4 o;
        o.x = sacc[it][0]; o.y = sacc[it][1]; o.z = sacc[it][2]; o.w = sacc[it][3];
        *reinterpret_cast<float4*>(&pout[(size_t)(chunk * BB + b) * (JJ * KK) + it * 256 + lo]) = o;
    }
}

// ---------------------------------------------------------------------------
// Reduce partials over NC chunks + squash. grid 2048 = (b*J + j), 64 threads.
// ---------------------------------------------------------------------------
__global__ __launch_bounds__(64)
void k_red_squash(const float* __restrict__ p, int NC, float scale,
                  const float* __restrict__ vprev, float* __restrict__ vout) {
    const int bj = blockIdx.x;   // b*J + j
    const int l  = threadIdx.x;
    const int k  = l & 31;
    const int h  = l >> 5;
    const int half = NC >> 1;
    float s = 0.f;
    for (int i = h * half; i < (h + 1) * half; ++i)
        s += p[((size_t)i * (BB * JJ) + bj) * KK + k];
    s += __shfl_xor(s, 32);
    s *= scale;
    float sq = s * s;
    sq += __shfl_xor(sq, 1);
    sq += __shfl_xor(sq, 2);
    sq += __shfl_xor(sq, 4);
    sq += __shfl_xor(sq, 8);
    sq += __shfl_xor(sq, 16);
    const float sc = sq / ((1.0f + sq) * sqrtf(sq + 1e-8f));
    float vo = s * sc;
    if (vprev) vo += vprev[bj * KK + k];
    if (h == 0) vout[bj * KK + k] = vo;
}

// ---------------------------------------------------------------------------
template <typename UT>
static void run_pipeline(const float* x, const float* W, float* out,
                         UT* u, float* p1, float* p2, float* v1, float* vv,
                         hipStream_t stream) {
    k1_uhat<UT><<<dim3(128, 4), 256, 0, stream>>>(x, W, u, p1);
    k_red_squash<<<2048, 64, 0, stream>>>(p1, 128, 1.0f / 64.0f, nullptr, v1);
    k_route<UT><<<dim3(32, 32), 256, 0, stream>>>(u, v1, p2);
    k_red_squash<<<2048, 64, 0, stream>>>(p2, 128, 1.0f, v1, vv);   // vv = v1+v2
    k_route<UT><<<dim3(32, 32), 256, 0, stream>>>(u, vv, p2);
    k_red_squash<<<2048, 64, 0, stream>>>(p2, 128, 1.0f, nullptr, out);
}

extern "C" void kernel_launch(void* const* d_in, const int* in_sizes, int n_in,
                              void* d_out, int out_size, void* d_ws, size_t ws_size,
                              hipStream_t stream) {
    const float* x = (const float*)d_in[0];   // [B][N][D]
    const float* W = (const float*)d_in[1];   // [N][J][D][K]
    float* out = (float*)d_out;               // [B][J][K]
    char*  ws  = (char*)d_ws;

    const size_t NU = (size_t)BB * NN * JJ * KK;       // 134217728 elements
    const size_t NP = (size_t)128 * BB * JJ * KK;      // 8388608 floats (partials)
    const size_t NV = (size_t)BB * JJ * KK;            // 65536 floats

    const size_t F32_NEED  = (NU + 2 * NP + 2 * NV) * 4;       // ~604.5 MB
    const size_t BF16_NEED = NU * 2 + (2 * NP + 2 * NV) * 4;   // ~336.1 MB

    if (ws_size >= F32_NEED) {
        float* u  = (float*)ws;
        float* p1 = u + NU;
        float* p2 = p1 + NP;
        float* v1 = p2 + NP;
        float* vv = v1 + NV;
        run_pipeline<float>(x, W, out, u, p1, p2, v1, vv, stream);
    } else {
        (void)BF16_NEED;
        unsigned short* u = (unsigned short*)ws;
        float* p1 = (float*)(ws + NU * 2);
        float* p2 = p1 + NP;
        float* v1 = p2 + NP;
        float* vv = v1 + NV;
        run_pipeline<unsigned short>(x, W, out, u, p1, p2, v1, vv, stream);
    }
}